// Round 20
// baseline (378.976 us; speedup 1.0000x reference)
//
#include <hip/hip_runtime.h>
#include <hip/hip_bf16.h>

typedef unsigned int uint;

// B=2, N=512, D=256, H=8, HD=32, DFF=1024
constexpr float EPS_ = 1e-5f;

#define DEV __device__ __forceinline__

DEV float gelu_(float x){ return 0.5f*x*(1.f + erff(x*0.70710678118654752f)); }

// ---------------- node LN + QKV: 2 rows/block, grid 512; block 0 also does edge-bias setup ----------------
__global__ __launch_bounds__(256) void k_qkv(
    const float* __restrict__ x,
    const float* __restrict__ g, const float* __restrict__ bta,
    const float* __restrict__ Wq, const float* __restrict__ bq,
    const float* __restrict__ Wk, const float* __restrict__ bk,
    const float* __restrict__ Wv, const float* __restrict__ bv,
    const float* __restrict__ eg, const float* __restrict__ ebb,
    const float* __restrict__ We, const float* __restrict__ be,
    float* __restrict__ GW, float* __restrict__ Av, float* __restrict__ Cv,
    float* __restrict__ q, float* __restrict__ k, float* __restrict__ v)
{
    const int t = threadIdx.x;
    __shared__ float redA2[4][8];
    __shared__ float redC2[4][8];
    if (blockIdx.x == 0) {
        float gd = eg[t], bd = ebb[t];
        float a_loc[8], c_loc[8];
        #pragma unroll
        for (int h = 0; h < 8; ++h) {
            float w = We[t*8 + h];
            float gw = gd * w;
            GW[t*8 + h] = gw;
            a_loc[h] = gw;
            c_loc[h] = bd * w;
        }
        #pragma unroll
        for (int h = 0; h < 8; ++h) {
            #pragma unroll
            for (int o = 32; o >= 1; o >>= 1) {
                a_loc[h] += __shfl_xor(a_loc[h], o);
                c_loc[h] += __shfl_xor(c_loc[h], o);
            }
        }
        if ((t & 63) == 0) {
            const int w = t >> 6;
            #pragma unroll
            for (int h = 0; h < 8; ++h) { redA2[w][h] = a_loc[h]; redC2[w][h] = c_loc[h]; }
        }
        __syncthreads();
        if (t < 8) {
            Av[t] = redA2[0][t] + redA2[1][t] + redA2[2][t] + redA2[3][t];
            Cv[t] = redC2[0][t] + redC2[1][t] + redC2[2][t] + redC2[3][t] + be[t];
        }
    }

    const int wid = t >> 6, l = t & 63;
    const int r0 = blockIdx.x << 1;
    __shared__ float sxT[256*2];          // [d][row]
    if (wid < 2) {
        const int row = r0 + wid;
        const float4 xv4 = ((const float4*)x)[row*64 + l];
        float s  = xv4.x + xv4.y + xv4.z + xv4.w;
        float q2 = xv4.x*xv4.x + xv4.y*xv4.y + xv4.z*xv4.z + xv4.w*xv4.w;
        #pragma unroll
        for (int o = 32; o >= 1; o >>= 1) { s += __shfl_xor(s, o); q2 += __shfl_xor(q2, o); }
        const float m = s * (1.f/256.f);
        const float rinv = rsqrtf(q2*(1.f/256.f) - m*m + EPS_);
        const float4 g4 = ((const float4*)g)[l];
        const float4 b4 = ((const float4*)bta)[l];
        sxT[(4*l+0)*2 + wid] = (xv4.x - m)*rinv*g4.x + b4.x;
        sxT[(4*l+1)*2 + wid] = (xv4.y - m)*rinv*g4.y + b4.y;
        sxT[(4*l+2)*2 + wid] = (xv4.z - m)*rinv*g4.z + b4.z;
        sxT[(4*l+3)*2 + wid] = (xv4.w - m)*rinv*g4.w + b4.w;
    }
    __syncthreads();
    float aq0 = bq[t], ak0 = bk[t], av0 = bv[t];
    float aq1 = aq0, ak1 = ak0, av1 = av0;
    for (int d = 0; d < 256; d += 2) {
        const float4 s4 = *((const float4*)&sxT[d*2]);
        const float wqa = Wq[d*256 + t], wqb = Wq[(d+1)*256 + t];
        const float wka = Wk[d*256 + t], wkb = Wk[(d+1)*256 + t];
        const float wva = Wv[d*256 + t], wvb = Wv[(d+1)*256 + t];
        aq0 = fmaf(s4.x, wqa, aq0); aq0 = fmaf(s4.z, wqb, aq0);
        aq1 = fmaf(s4.y, wqa, aq1); aq1 = fmaf(s4.w, wqb, aq1);
        ak0 = fmaf(s4.x, wka, ak0); ak0 = fmaf(s4.z, wkb, ak0);
        ak1 = fmaf(s4.y, wka, ak1); ak1 = fmaf(s4.w, wkb, ak1);
        av0 = fmaf(s4.x, wva, av0); av0 = fmaf(s4.z, wvb, av0);
        av1 = fmaf(s4.y, wva, av1); av1 = fmaf(s4.w, wvb, av1);
    }
    q[(r0+0)*256 + t] = aq0; q[(r0+1)*256 + t] = aq1;
    k[(r0+0)*256 + t] = ak0; k[(r0+1)*256 + t] = ak1;
    v[(r0+0)*256 + t] = av0; v[(r0+1)*256 + t] = av1;
}

// ---------------- fused: edge LN bias + QK^T + softmax + PV for one (b,i) ----------------
// T3 "2-phase" single-barrier double-buffer: iteration cc issues loads for chunk cc+1,
// computes chunk cc from buf[cc&1] (hides latency), writes buf[(cc+1)&1], ONE barrier.
// Stride-17 rows (coprime 32) -> conflict-free b128 reads. 2x17.4KB staging; sb unions buf0.
__global__ __launch_bounds__(256, 4) void k_eattn(
    const float4* __restrict__ ep,        // edge as float4: 64 per 256-elem row
    const int*   __restrict__ msk,        // (B,N,N)
    const float* __restrict__ GWg, const float* __restrict__ Avec, const float* __restrict__ Cvec,
    const float* __restrict__ qg, const float4* __restrict__ kg4, const float* __restrict__ vg,
    float* __restrict__ ao)               // (B,N,D) f32
{
    __shared__ float smem[8704];          // buf0 [0,4352) ∪ sb(4096); buf1 [4352,8704)
    __shared__ float sqv[256];            // q row, pre-scaled
    __shared__ float sden[8];
    const int t = threadIdx.x;
    const int bi = blockIdx.x;            // b*512 + i
    const int b = bi >> 9;
    sqv[t] = qg[(size_t)bi*256 + t] * 0.17677669529663687f;   // 1/sqrt(32)
    __syncthreads();

    const int r = t >> 2, u = t & 3;      // staging coords; thread writes rows {r,r+64,r+128,r+192}
    const int wr0 = r*17 + (u << 2);      // float offset within a buffer (stride 17)

    float S[2][8], qk[2][8], mval[2], rinv[2], mb[2];

    #pragma unroll
    for (int half = 0; half < 2; ++half) {
        const long long rowBase = ((long long)bi << 9) + (half << 8);   // edge row (b,i,j0)
        const int krow0 = (b << 9) + (half << 8);                       // key row (b,j0)
        float sum = 0.f, ssq = 0.f;
        #pragma unroll
        for (int h = 0; h < 8; ++h) { S[half][h] = 0.f; qk[half][h] = 0.f; }

        float4 R0, R1, R2, R3;
        // prologue: chunk 0 (edge c=0) -> buf0
        R0 = ep[(rowBase + r      )*64 + u];
        R1 = ep[(rowBase + r +  64)*64 + u];
        R2 = ep[(rowBase + r + 128)*64 + u];
        R3 = ep[(rowBase + r + 192)*64 + u];
        {
            float* buf = smem;
            *((float4*)&buf[wr0          ]) = R0;
            *((float4*)&buf[wr0 + 64*17  ]) = R1;
            *((float4*)&buf[wr0 + 128*17 ]) = R2;
            *((float4*)&buf[wr0 + 192*17 ]) = R3;
        }
        __syncthreads();

        // 32 chunks: cc<16 edge chunk cc; cc>=16 K chunk cc-16. ONE barrier per chunk.
        for (int cc = 0; cc < 32; ++cc) {
            // issue next chunk's loads (in flight during compute)
            if (cc + 1 < 32) {
                const int nc = cc + 1;
                if (nc < 16) {
                    R0 = ep[(rowBase + r      )*64 + (nc << 2) + u];
                    R1 = ep[(rowBase + r +  64)*64 + (nc << 2) + u];
                    R2 = ep[(rowBase + r + 128)*64 + (nc << 2) + u];
                    R3 = ep[(rowBase + r + 192)*64 + (nc << 2) + u];
                } else {
                    const int kc = nc - 16;
                    R0 = kg4[(size_t)(krow0 + r      )*64 + (kc << 2) + u];
                    R1 = kg4[(size_t)(krow0 + r +  64)*64 + (kc << 2) + u];
                    R2 = kg4[(size_t)(krow0 + r + 128)*64 + (kc << 2) + u];
                    R3 = kg4[(size_t)(krow0 + r + 192)*64 + (kc << 2) + u];
                }
            }
            // compute chunk cc from buf[cc&1]
            const float* srow = &smem[(cc & 1) ? 4352 : 0] + t*17;
            if (cc < 16) {
                const int d0 = cc << 4;
                #pragma unroll
                for (int j4 = 0; j4 < 4; ++j4) {
                    const float4 e4 = *((const float4*)&srow[j4 << 2]);
                    #pragma unroll
                    for (int uu = 0; uu < 4; ++uu) {
                        const float e = (uu==0) ? e4.x : (uu==1) ? e4.y : (uu==2) ? e4.z : e4.w;
                        const float* gw = &GWg[(size_t)(d0 + (j4 << 2) + uu) << 3];  // uniform -> SGPR
                        sum += e;
                        ssq = fmaf(e, e, ssq);
                        S[half][0] = fmaf(e, gw[0], S[half][0]); S[half][1] = fmaf(e, gw[1], S[half][1]);
                        S[half][2] = fmaf(e, gw[2], S[half][2]); S[half][3] = fmaf(e, gw[3], S[half][3]);
                        S[half][4] = fmaf(e, gw[4], S[half][4]); S[half][5] = fmaf(e, gw[5], S[half][5]);
                        S[half][6] = fmaf(e, gw[6], S[half][6]); S[half][7] = fmaf(e, gw[7], S[half][7]);
                    }
                }
            } else {
                const int kc = cc - 16;
                const float4* q4p = (const float4*)&sqv[kc << 4];   // uniform broadcast
                float acc = qk[half][kc >> 1];
                #pragma unroll
                for (int j4 = 0; j4 < 4; ++j4) {
                    const float4 k4 = *((const float4*)&srow[j4 << 2]);
                    const float4 q4 = q4p[j4];
                    acc = fmaf(k4.x, q4.x, acc); acc = fmaf(k4.y, q4.y, acc);
                    acc = fmaf(k4.z, q4.z, acc); acc = fmaf(k4.w, q4.w, acc);
                }
                qk[half][kc >> 1] = acc;
            }
            // write next chunk into buf[(cc+1)&1] (loads have drained under compute)
            if (cc + 1 < 32) {
                float* buf = &smem[((cc + 1) & 1) ? 4352 : 0];
                *((float4*)&buf[wr0          ]) = R0;
                *((float4*)&buf[wr0 + 64*17  ]) = R1;
                *((float4*)&buf[wr0 + 128*17 ]) = R2;
                *((float4*)&buf[wr0 + 192*17 ]) = R3;
            }
            __syncthreads();   // publishes buf[(cc+1)&1]; guards overwrite 2 iters out
        }

        mval[half] = sum * (1.f/256.f);
        rinv[half] = rsqrtf(ssq*(1.f/256.f) - mval[half]*mval[half] + EPS_);
        mb[half]   = (msk[rowBase + t] == 0) ? -1e30f : 0.f;
    }

    // ---- write scores into sb (aliases smem; staging is dead now) ----
    float* sb = smem;
    #pragma unroll
    for (int half = 0; half < 2; ++half) {
        const int jrow = (half << 8) + t;
        #pragma unroll
        for (int h = 0; h < 8; ++h)
            sb[h*512 + jrow] = qk[half][h]
                             + rinv[half] * (S[half][h] - mval[half] * Avec[h])
                             + Cvec[h] + mb[half];
    }
    __syncthreads();

    // ---- softmax: (h = t>>5, l = t&31) owns keys j in [16l, 16l+16) ----
    {
        const int h = t >> 5, l = t & 31;
        float* base = &sb[h*512 + (l << 4)];
        float4 s4[4];
        float pmax = -3.0e38f;
        #pragma unroll
        for (int i = 0; i < 4; ++i) {
            s4[i] = *((const float4*)&base[i << 2]);
            pmax = fmaxf(pmax, fmaxf(fmaxf(s4[i].x, s4[i].y), fmaxf(s4[i].z, s4[i].w)));
        }
        #pragma unroll
        for (int o = 16; o >= 1; o >>= 1) pmax = fmaxf(pmax, __shfl_xor(pmax, o));
        float psum = 0.f;
        #pragma unroll
        for (int i = 0; i < 4; ++i) {
            const float p0 = __expf(s4[i].x - pmax), p1 = __expf(s4[i].y - pmax);
            const float p2 = __expf(s4[i].z - pmax), p3 = __expf(s4[i].w - pmax);
            psum += (p0 + p1) + (p2 + p3);
            *((float4*)&base[i << 2]) = make_float4(p0, p1, p2, p3);
        }
        #pragma unroll
        for (int o = 16; o >= 1; o >>= 1) psum += __shfl_xor(psum, o);
        if (l == 0) sden[h] = psum;
    }
    __syncthreads();

    // ---- PV: thread t owns output channel t; prob reads are uniform broadcasts ----
    {
        const int h = t >> 5;
        const float* vb = vg + ((size_t)b << 9)*256 + t;
        const float4* spr4 = (const float4*)&sb[h*512];
        float a0 = 0.f, a1 = 0.f, a2 = 0.f, a3 = 0.f;
        for (int j4 = 0; j4 < 128; ++j4) {
            const float4 p4 = spr4[j4];
            const float* vj = vb + ((size_t)j4 << 2)*256;
            a0 = fmaf(p4.x, vj[0],   a0);
            a1 = fmaf(p4.y, vj[256], a1);
            a2 = fmaf(p4.z, vj[512], a2);
            a3 = fmaf(p4.w, vj[768], a3);
        }
        ao[(size_t)bi*256 + t] = (a0+a1+a2+a3) / sden[h];
    }
}

// ---------------- fused proj + residual + FFN: 2 rows/block, grid 512 (r13 champion) ----------------
__global__ __launch_bounds__(256) void k_projff(
    const float* __restrict__ at, const float* __restrict__ Wo,
    const float* __restrict__ bo, const float* __restrict__ x,
    const float* __restrict__ g, const float* __restrict__ bb,
    const float* __restrict__ W1, const float* __restrict__ b1,
    const float* __restrict__ W2, const float* __restrict__ b2,
    float* __restrict__ out)
{
    const int t = threadIdx.x;
    const int wid = t >> 6, l = t & 63;
    const int r0 = blockIdx.x << 1;
    __shared__ float saT[256*2];          // [d][row] attn-out transposed
    __shared__ float shT[256*2];          // [d][row] LN values
    __shared__ float sfT[2*1024];         // [row][dff] gelu values
    __shared__ float sx1[2][256];         // x1 rows (residual + LN input)

    if (wid < 2) {
        const float4 a4 = ((const float4*)at)[(r0 + wid)*64 + l];
        saT[(4*l+0)*2 + wid] = a4.x;
        saT[(4*l+1)*2 + wid] = a4.y;
        saT[(4*l+2)*2 + wid] = a4.z;
        saT[(4*l+3)*2 + wid] = a4.w;
    }
    __syncthreads();
    // proj + residual -> x1 in LDS
    {
        float A0 = bo[t], A1 = A0;
        for (int d = 0; d < 256; d += 2) {
            const float4 s4 = *((const float4*)&saT[d*2]);
            const float wa = Wo[d*256 + t], wb = Wo[(d+1)*256 + t];
            A0 = fmaf(s4.x, wa, A0); A0 = fmaf(s4.z, wb, A0);
            A1 = fmaf(s4.y, wa, A1); A1 = fmaf(s4.w, wb, A1);
        }
        sx1[0][t] = A0 + x[(r0+0)*256 + t];
        sx1[1][t] = A1 + x[(r0+1)*256 + t];
    }
    __syncthreads();
    // LN of x1 rows (waves 0,1), transposed into shT
    if (wid < 2) {
        const float4 xv4 = *((const float4*)&sx1[wid][4*l]);
        float s  = xv4.x + xv4.y + xv4.z + xv4.w;
        float q2 = xv4.x*xv4.x + xv4.y*xv4.y + xv4.z*xv4.z + xv4.w*xv4.w;
        #pragma unroll
        for (int o = 32; o >= 1; o >>= 1) { s += __shfl_xor(s, o); q2 += __shfl_xor(q2, o); }
        const float m = s * (1.f/256.f);
        const float rinv = rsqrtf(q2*(1.f/256.f) - m*m + EPS_);
        const float4 g4 = ((const float4*)g)[l];
        const float4 b4 = ((const float4*)bb)[l];
        shT[(4*l+0)*2 + wid] = (xv4.x - m)*rinv*g4.x + b4.x;
        shT[(4*l+1)*2 + wid] = (xv4.y - m)*rinv*g4.y + b4.y;
        shT[(4*l+2)*2 + wid] = (xv4.z - m)*rinv*g4.z + b4.z;
        shT[(4*l+3)*2 + wid] = (xv4.w - m)*rinv*g4.w + b4.w;
    }
    __syncthreads();
    // W1 + gelu: thread owns channels 4t..4t+3, rows 0..1
    {
        const float4 bc = ((const float4*)b1)[t];
        float A00 = bc.x, A01 = bc.x;
        float A10 = bc.y, A11 = bc.y;
        float A20 = bc.z, A21 = bc.z;
        float A30 = bc.w, A31 = bc.w;
        const float4* W14 = (const float4*)W1;
        for (int d = 0; d < 256; ++d) {
            const float2 s2 = *((const float2*)&shT[d*2]);
            const float4 w4 = W14[d*256 + t];
            A00 = fmaf(s2.x, w4.x, A00); A01 = fmaf(s2.y, w4.x, A01);
            A10 = fmaf(s2.x, w4.y, A10); A11 = fmaf(s2.y, w4.y, A11);
            A20 = fmaf(s2.x, w4.z, A20); A21 = fmaf(s2.y, w4.z, A21);
            A30 = fmaf(s2.x, w4.w, A30); A31 = fmaf(s2.y, w4.w, A31);
        }
        *((float4*)&sfT[0*1024 + 4*t]) = make_float4(gelu_(A00), gelu_(A10), gelu_(A20), gelu_(A30));
        *((float4*)&sfT[1*1024 + 4*t]) = make_float4(gelu_(A01), gelu_(A11), gelu_(A21), gelu_(A31));
    }
    __syncthreads();
    // W2 + residual
    {
        float AO0 = b2[t], AO1 = AO0;
        for (int kk = 0; kk < 1024; ++kk) {
            const float w = W2[kk*256 + t];
            AO0 = fmaf(sfT[kk],        w, AO0);
            AO1 = fmaf(sfT[1024 + kk], w, AO1);
        }
        out[(r0+0)*256 + t] = AO0 + sx1[0][t];
        out[(r0+1)*256 + t] = AO1 + sx1[1][t];
    }
}

extern "C" void kernel_launch(void* const* d_in, const int* in_sizes, int n_in,
                              void* d_out, int out_size, void* d_ws, size_t ws_size,
                              hipStream_t stream) {
    const float* x   = (const float*)d_in[0];
    const float* ef  = (const float*)d_in[1];
    const int*   am  = (const int*)d_in[2];
    const float* ng  = (const float*)d_in[3];
    const float* nb  = (const float*)d_in[4];
    const float* eg  = (const float*)d_in[5];
    const float* ebb = (const float*)d_in[6];
    const float* Wq  = (const float*)d_in[7];
    const float* bq  = (const float*)d_in[8];
    const float* Wk  = (const float*)d_in[9];
    const float* bk  = (const float*)d_in[10];
    const float* Wv  = (const float*)d_in[11];
    const float* bv  = (const float*)d_in[12];
    const float* Wo  = (const float*)d_in[13];
    const float* bo  = (const float*)d_in[14];
    const float* We  = (const float*)d_in[15];
    const float* be  = (const float*)d_in[16];
    const float* fg  = (const float*)d_in[17];
    const float* fb  = (const float*)d_in[18];
    const float* W1  = (const float*)d_in[19];
    const float* b1  = (const float*)d_in[20];
    const float* W2  = (const float*)d_in[21];
    const float* b2  = (const float*)d_in[22];

    float* ws  = (float*)d_ws;
    float* GW  = ws;                      // 2048 f
    float* Av  = ws + 2048;               // 8 f
    float* Cv  = ws + 2064;               // 8 f
    float* q   = ws + 4096;               // 262144 f (B,N,D)
    float* k   = q  + 262144;
    float* v   = k  + 262144;
    float* ao  = v  + 262144;             // 262144 f (B,N,D)

    hipLaunchKernelGGL(k_qkv, dim3(512), dim3(256), 0, stream,
                       x, ng, nb, Wq, bq, Wk, bk, Wv, bv,
                       eg, ebb, We, be, GW, Av, Cv, q, k, v);
    hipLaunchKernelGGL(k_eattn, dim3(1024), dim3(256), 0, stream,
                       (const float4*)ef, am, GW, Av, Cv, q, (const float4*)k, v, ao);
    hipLaunchKernelGGL(k_projff, dim3(512), dim3(256), 0, stream,
                       ao, Wo, bo, x, fg, fb, W1, b1, W2, b2, (float*)d_out);
}

// Round 21
// 271.795 us; speedup vs baseline: 1.3943x; 1.3943x over previous
//
#include <hip/hip_runtime.h>
#include <hip/hip_bf16.h>

typedef unsigned int uint;

// B=2, N=512, D=256, H=8, HD=32, DFF=1024
constexpr float EPS_ = 1e-5f;

#define DEV __device__ __forceinline__

DEV float gelu_(float x){ return 0.5f*x*(1.f + erff(x*0.70710678118654752f)); }

// ---------------- node LN + QKV: 2 rows/block, grid 512; block 0 also does edge-bias setup ----------------
__global__ __launch_bounds__(256) void k_qkv(
    const float* __restrict__ x,
    const float* __restrict__ g, const float* __restrict__ bta,
    const float* __restrict__ Wq, const float* __restrict__ bq,
    const float* __restrict__ Wk, const float* __restrict__ bk,
    const float* __restrict__ Wv, const float* __restrict__ bv,
    const float* __restrict__ eg, const float* __restrict__ ebb,
    const float* __restrict__ We, const float* __restrict__ be,
    float* __restrict__ GW, float* __restrict__ Av, float* __restrict__ Cv,
    float* __restrict__ q, float* __restrict__ k, float* __restrict__ v)
{
    const int t = threadIdx.x;
    __shared__ float redA2[4][8];
    __shared__ float redC2[4][8];
    if (blockIdx.x == 0) {
        float gd = eg[t], bd = ebb[t];
        float a_loc[8], c_loc[8];
        #pragma unroll
        for (int h = 0; h < 8; ++h) {
            float w = We[t*8 + h];
            float gw = gd * w;
            GW[t*8 + h] = gw;
            a_loc[h] = gw;
            c_loc[h] = bd * w;
        }
        #pragma unroll
        for (int h = 0; h < 8; ++h) {
            #pragma unroll
            for (int o = 32; o >= 1; o >>= 1) {
                a_loc[h] += __shfl_xor(a_loc[h], o);
                c_loc[h] += __shfl_xor(c_loc[h], o);
            }
        }
        if ((t & 63) == 0) {
            const int w = t >> 6;
            #pragma unroll
            for (int h = 0; h < 8; ++h) { redA2[w][h] = a_loc[h]; redC2[w][h] = c_loc[h]; }
        }
        __syncthreads();
        if (t < 8) {
            Av[t] = redA2[0][t] + redA2[1][t] + redA2[2][t] + redA2[3][t];
            Cv[t] = redC2[0][t] + redC2[1][t] + redC2[2][t] + redC2[3][t] + be[t];
        }
    }

    const int wid = t >> 6, l = t & 63;
    const int r0 = blockIdx.x << 1;
    __shared__ float sxT[256*2];          // [d][row]
    if (wid < 2) {
        const int row = r0 + wid;
        const float4 xv4 = ((const float4*)x)[row*64 + l];
        float s  = xv4.x + xv4.y + xv4.z + xv4.w;
        float q2 = xv4.x*xv4.x + xv4.y*xv4.y + xv4.z*xv4.z + xv4.w*xv4.w;
        #pragma unroll
        for (int o = 32; o >= 1; o >>= 1) { s += __shfl_xor(s, o); q2 += __shfl_xor(q2, o); }
        const float m = s * (1.f/256.f);
        const float rinv = rsqrtf(q2*(1.f/256.f) - m*m + EPS_);
        const float4 g4 = ((const float4*)g)[l];
        const float4 b4 = ((const float4*)bta)[l];
        sxT[(4*l+0)*2 + wid] = (xv4.x - m)*rinv*g4.x + b4.x;
        sxT[(4*l+1)*2 + wid] = (xv4.y - m)*rinv*g4.y + b4.y;
        sxT[(4*l+2)*2 + wid] = (xv4.z - m)*rinv*g4.z + b4.z;
        sxT[(4*l+3)*2 + wid] = (xv4.w - m)*rinv*g4.w + b4.w;
    }
    __syncthreads();
    float aq0 = bq[t], ak0 = bk[t], av0 = bv[t];
    float aq1 = aq0, ak1 = ak0, av1 = av0;
    for (int d = 0; d < 256; d += 2) {
        const float4 s4 = *((const float4*)&sxT[d*2]);
        const float wqa = Wq[d*256 + t], wqb = Wq[(d+1)*256 + t];
        const float wka = Wk[d*256 + t], wkb = Wk[(d+1)*256 + t];
        const float wva = Wv[d*256 + t], wvb = Wv[(d+1)*256 + t];
        aq0 = fmaf(s4.x, wqa, aq0); aq0 = fmaf(s4.z, wqb, aq0);
        aq1 = fmaf(s4.y, wqa, aq1); aq1 = fmaf(s4.w, wqb, aq1);
        ak0 = fmaf(s4.x, wka, ak0); ak0 = fmaf(s4.z, wkb, ak0);
        ak1 = fmaf(s4.y, wka, ak1); ak1 = fmaf(s4.w, wkb, ak1);
        av0 = fmaf(s4.x, wva, av0); av0 = fmaf(s4.z, wvb, av0);
        av1 = fmaf(s4.y, wva, av1); av1 = fmaf(s4.w, wvb, av1);
    }
    q[(r0+0)*256 + t] = aq0; q[(r0+1)*256 + t] = aq1;
    k[(r0+0)*256 + t] = ak0; k[(r0+1)*256 + t] = ak1;
    v[(r0+0)*256 + t] = av0; v[(r0+1)*256 + t] = av1;
}

// ---------------- fused: edge LN bias + QK^T + softmax + PV for one (b,i) ----------------
// CHAMPION (r13/r17, 271.2/272.6 us): 16-float chunks, stride-20 LDS,
// staging∪scores union -> 5 blocks/CU.
__global__ __launch_bounds__(256, 5) void k_eattn(
    const float4* __restrict__ ep,        // edge as float4: 64 per 256-elem row
    const int*   __restrict__ msk,        // (B,N,N)
    const float* __restrict__ GWg, const float* __restrict__ Avec, const float* __restrict__ Cvec,
    const float* __restrict__ qg, const float4* __restrict__ kg4, const float* __restrict__ vg,
    float* __restrict__ ao)               // (B,N,D) f32
{
    __shared__ float smem[5120];          // slds (256*20) ∪ sb (4096)
    __shared__ float sqv[256];            // q row, pre-scaled
    __shared__ float sden[8];
    const int t = threadIdx.x;
    const int bi = blockIdx.x;            // b*512 + i
    const int b = bi >> 9;
    sqv[t] = qg[(size_t)bi*256 + t] * 0.17677669529663687f;   // 1/sqrt(32)
    __syncthreads();

    const int r = t >> 2, u = t & 3;      // staging coords

    float S[2][8], qk[2][8], mval[2], rinv[2], mb[2];

    #pragma unroll
    for (int half = 0; half < 2; ++half) {
        const long long rowBase = ((long long)bi << 9) + (half << 8);   // edge row (b,i,j0)
        const int krow0 = (b << 9) + (half << 8);                       // key row (b,j0)
        float sum = 0.f, ssq = 0.f;
        #pragma unroll
        for (int h = 0; h < 8; ++h) { S[half][h] = 0.f; qk[half][h] = 0.f; }

        // ---- edge chunks: 16 x 16 floats per row ----
        for (int c = 0; c < 16; ++c) {
            *((float4*)&smem[(r      )*20 + (u << 2)]) = ep[(rowBase + r      )*64 + (c << 2) + u];
            *((float4*)&smem[(r +  64)*20 + (u << 2)]) = ep[(rowBase + r +  64)*64 + (c << 2) + u];
            *((float4*)&smem[(r + 128)*20 + (u << 2)]) = ep[(rowBase + r + 128)*64 + (c << 2) + u];
            *((float4*)&smem[(r + 192)*20 + (u << 2)]) = ep[(rowBase + r + 192)*64 + (c << 2) + u];
            __syncthreads();
            const float* srow = &smem[t*20];
            const int d0 = c << 4;
            #pragma unroll
            for (int j4 = 0; j4 < 4; ++j4) {
                const float4 e4 = *((const float4*)&srow[j4 << 2]);
                #pragma unroll
                for (int uu = 0; uu < 4; ++uu) {
                    const float e = (uu==0) ? e4.x : (uu==1) ? e4.y : (uu==2) ? e4.z : e4.w;
                    const float* gw = &GWg[(size_t)(d0 + (j4 << 2) + uu) << 3];  // uniform -> SGPR
                    sum += e;
                    ssq = fmaf(e, e, ssq);
                    S[half][0] = fmaf(e, gw[0], S[half][0]); S[half][1] = fmaf(e, gw[1], S[half][1]);
                    S[half][2] = fmaf(e, gw[2], S[half][2]); S[half][3] = fmaf(e, gw[3], S[half][3]);
                    S[half][4] = fmaf(e, gw[4], S[half][4]); S[half][5] = fmaf(e, gw[5], S[half][5]);
                    S[half][6] = fmaf(e, gw[6], S[half][6]); S[half][7] = fmaf(e, gw[7], S[half][7]);
                }
            }
            __syncthreads();
        }

        // ---- K chunks: 16 x 16 floats per row; chunk c belongs to head c>>1 ----
        for (int c = 0; c < 16; ++c) {
            *((float4*)&smem[(r      )*20 + (u << 2)]) = kg4[(size_t)(krow0 + r      )*64 + (c << 2) + u];
            *((float4*)&smem[(r +  64)*20 + (u << 2)]) = kg4[(size_t)(krow0 + r +  64)*64 + (c << 2) + u];
            *((float4*)&smem[(r + 128)*20 + (u << 2)]) = kg4[(size_t)(krow0 + r + 128)*64 + (c << 2) + u];
            *((float4*)&smem[(r + 192)*20 + (u << 2)]) = kg4[(size_t)(krow0 + r + 192)*64 + (c << 2) + u];
            __syncthreads();
            const float* srow = &smem[t*20];
            const float4* q4p = (const float4*)&sqv[c << 4];   // uniform broadcast
            float acc = qk[half][c >> 1];
            #pragma unroll
            for (int j4 = 0; j4 < 4; ++j4) {
                const float4 k4 = *((const float4*)&srow[j4 << 2]);
                const float4 q4 = q4p[j4];
                acc = fmaf(k4.x, q4.x, acc); acc = fmaf(k4.y, q4.y, acc);
                acc = fmaf(k4.z, q4.z, acc); acc = fmaf(k4.w, q4.w, acc);
            }
            qk[half][c >> 1] = acc;
            __syncthreads();
        }

        mval[half] = sum * (1.f/256.f);
        rinv[half] = rsqrtf(ssq*(1.f/256.f) - mval[half]*mval[half] + EPS_);
        mb[half]   = (msk[rowBase + t] == 0) ? -1e30f : 0.f;
    }

    // ---- write scores into sb (aliases smem; staging is dead now) ----
    float* sb = smem;
    #pragma unroll
    for (int half = 0; half < 2; ++half) {
        const int jrow = (half << 8) + t;
        #pragma unroll
        for (int h = 0; h < 8; ++h)
            sb[h*512 + jrow] = qk[half][h]
                             + rinv[half] * (S[half][h] - mval[half] * Avec[h])
                             + Cvec[h] + mb[half];
    }
    __syncthreads();

    // ---- softmax: (h = t>>5, l = t&31) owns keys j in [16l, 16l+16) ----
    {
        const int h = t >> 5, l = t & 31;
        float* base = &sb[h*512 + (l << 4)];
        float4 s4[4];
        float pmax = -3.0e38f;
        #pragma unroll
        for (int i = 0; i < 4; ++i) {
            s4[i] = *((const float4*)&base[i << 2]);
            pmax = fmaxf(pmax, fmaxf(fmaxf(s4[i].x, s4[i].y), fmaxf(s4[i].z, s4[i].w)));
        }
        #pragma unroll
        for (int o = 16; o >= 1; o >>= 1) pmax = fmaxf(pmax, __shfl_xor(pmax, o));
        float psum = 0.f;
        #pragma unroll
        for (int i = 0; i < 4; ++i) {
            const float p0 = __expf(s4[i].x - pmax), p1 = __expf(s4[i].y - pmax);
            const float p2 = __expf(s4[i].z - pmax), p3 = __expf(s4[i].w - pmax);
            psum += (p0 + p1) + (p2 + p3);
            *((float4*)&base[i << 2]) = make_float4(p0, p1, p2, p3);
        }
        #pragma unroll
        for (int o = 16; o >= 1; o >>= 1) psum += __shfl_xor(psum, o);
        if (l == 0) sden[h] = psum;
    }
    __syncthreads();

    // ---- PV: thread t owns output channel t; prob reads are uniform broadcasts ----
    {
        const int h = t >> 5;
        const float* vb = vg + ((size_t)b << 9)*256 + t;
        const float4* spr4 = (const float4*)&sb[h*512];
        float a0 = 0.f, a1 = 0.f, a2 = 0.f, a3 = 0.f;
        for (int j4 = 0; j4 < 128; ++j4) {
            const float4 p4 = spr4[j4];
            const float* vj = vb + ((size_t)j4 << 2)*256;
            a0 = fmaf(p4.x, vj[0],   a0);
            a1 = fmaf(p4.y, vj[256], a1);
            a2 = fmaf(p4.z, vj[512], a2);
            a3 = fmaf(p4.w, vj[768], a3);
        }
        ao[(size_t)bi*256 + t] = (a0+a1+a2+a3) / sden[h];
    }
}

// ---------------- fused proj + residual + FFN: 2 rows/block, grid 512 (r13 champion) ----------------
__global__ __launch_bounds__(256) void k_projff(
    const float* __restrict__ at, const float* __restrict__ Wo,
    const float* __restrict__ bo, const float* __restrict__ x,
    const float* __restrict__ g, const float* __restrict__ bb,
    const float* __restrict__ W1, const float* __restrict__ b1,
    const float* __restrict__ W2, const float* __restrict__ b2,
    float* __restrict__ out)
{
    const int t = threadIdx.x;
    const int wid = t >> 6, l = t & 63;
    const int r0 = blockIdx.x << 1;
    __shared__ float saT[256*2];          // [d][row] attn-out transposed
    __shared__ float shT[256*2];          // [d][row] LN values
    __shared__ float sfT[2*1024];         // [row][dff] gelu values
    __shared__ float sx1[2][256];         // x1 rows (residual + LN input)

    if (wid < 2) {
        const float4 a4 = ((const float4*)at)[(r0 + wid)*64 + l];
        saT[(4*l+0)*2 + wid] = a4.x;
        saT[(4*l+1)*2 + wid] = a4.y;
        saT[(4*l+2)*2 + wid] = a4.z;
        saT[(4*l+3)*2 + wid] = a4.w;
    }
    __syncthreads();
    // proj + residual -> x1 in LDS
    {
        float A0 = bo[t], A1 = A0;
        for (int d = 0; d < 256; d += 2) {
            const float4 s4 = *((const float4*)&saT[d*2]);
            const float wa = Wo[d*256 + t], wb = Wo[(d+1)*256 + t];
            A0 = fmaf(s4.x, wa, A0); A0 = fmaf(s4.z, wb, A0);
            A1 = fmaf(s4.y, wa, A1); A1 = fmaf(s4.w, wb, A1);
        }
        sx1[0][t] = A0 + x[(r0+0)*256 + t];
        sx1[1][t] = A1 + x[(r0+1)*256 + t];
    }
    __syncthreads();
    // LN of x1 rows (waves 0,1), transposed into shT
    if (wid < 2) {
        const float4 xv4 = *((const float4*)&sx1[wid][4*l]);
        float s  = xv4.x + xv4.y + xv4.z + xv4.w;
        float q2 = xv4.x*xv4.x + xv4.y*xv4.y + xv4.z*xv4.z + xv4.w*xv4.w;
        #pragma unroll
        for (int o = 32; o >= 1; o >>= 1) { s += __shfl_xor(s, o); q2 += __shfl_xor(q2, o); }
        const float m = s * (1.f/256.f);
        const float rinv = rsqrtf(q2*(1.f/256.f) - m*m + EPS_);
        const float4 g4 = ((const float4*)g)[l];
        const float4 b4 = ((const float4*)bb)[l];
        shT[(4*l+0)*2 + wid] = (xv4.x - m)*rinv*g4.x + b4.x;
        shT[(4*l+1)*2 + wid] = (xv4.y - m)*rinv*g4.y + b4.y;
        shT[(4*l+2)*2 + wid] = (xv4.z - m)*rinv*g4.z + b4.z;
        shT[(4*l+3)*2 + wid] = (xv4.w - m)*rinv*g4.w + b4.w;
    }
    __syncthreads();
    // W1 + gelu: thread owns channels 4t..4t+3, rows 0..1
    {
        const float4 bc = ((const float4*)b1)[t];
        float A00 = bc.x, A01 = bc.x;
        float A10 = bc.y, A11 = bc.y;
        float A20 = bc.z, A21 = bc.z;
        float A30 = bc.w, A31 = bc.w;
        const float4* W14 = (const float4*)W1;
        for (int d = 0; d < 256; ++d) {
            const float2 s2 = *((const float2*)&shT[d*2]);
            const float4 w4 = W14[d*256 + t];
            A00 = fmaf(s2.x, w4.x, A00); A01 = fmaf(s2.y, w4.x, A01);
            A10 = fmaf(s2.x, w4.y, A10); A11 = fmaf(s2.y, w4.y, A11);
            A20 = fmaf(s2.x, w4.z, A20); A21 = fmaf(s2.y, w4.z, A21);
            A30 = fmaf(s2.x, w4.w, A30); A31 = fmaf(s2.y, w4.w, A31);
        }
        *((float4*)&sfT[0*1024 + 4*t]) = make_float4(gelu_(A00), gelu_(A10), gelu_(A20), gelu_(A30));
        *((float4*)&sfT[1*1024 + 4*t]) = make_float4(gelu_(A01), gelu_(A11), gelu_(A21), gelu_(A31));
    }
    __syncthreads();
    // W2 + residual
    {
        float AO0 = b2[t], AO1 = AO0;
        for (int kk = 0; kk < 1024; ++kk) {
            const float w = W2[kk*256 + t];
            AO0 = fmaf(sfT[kk],        w, AO0);
            AO1 = fmaf(sfT[1024 + kk], w, AO1);
        }
        out[(r0+0)*256 + t] = AO0 + sx1[0][t];
        out[(r0+1)*256 + t] = AO1 + sx1[1][t];
    }
}

extern "C" void kernel_launch(void* const* d_in, const int* in_sizes, int n_in,
                              void* d_out, int out_size, void* d_ws, size_t ws_size,
                              hipStream_t stream) {
    const float* x   = (const float*)d_in[0];
    const float* ef  = (const float*)d_in[1];
    const int*   am  = (const int*)d_in[2];
    const float* ng  = (const float*)d_in[3];
    const float* nb  = (const float*)d_in[4];
    const float* eg  = (const float*)d_in[5];
    const float* ebb = (const float*)d_in[6];
    const float* Wq  = (const float*)d_in[7];
    const float* bq  = (const float*)d_in[8];
    const float* Wk  = (const float*)d_in[9];
    const float* bk  = (const float*)d_in[10];
    const float* Wv  = (const float*)d_in[11];
    const float* bv  = (const float*)d_in[12];
    const float* Wo  = (const float*)d_in[13];
    const float* bo  = (const float*)d_in[14];
    const float* We  = (const float*)d_in[15];
    const float* be  = (const float*)d_in[16];
    const float* fg  = (const float*)d_in[17];
    const float* fb  = (const float*)d_in[18];
    const float* W1  = (const float*)d_in[19];
    const float* b1  = (const float*)d_in[20];
    const float* W2  = (const float*)d_in[21];
    const float* b2  = (const float*)d_in[22];

    float* ws  = (float*)d_ws;
    float* GW  = ws;                      // 2048 f
    float* Av  = ws + 2048;               // 8 f
    float* Cv  = ws + 2064;               // 8 f
    float* q   = ws + 4096;               // 262144 f (B,N,D)
    float* k   = q  + 262144;
    float* v   = k  + 262144;
    float* ao  = v  + 262144;             // 262144 f (B,N,D)

    hipLaunchKernelGGL(k_qkv, dim3(512), dim3(256), 0, stream,
                       x, ng, nb, Wq, bq, Wk, bk, Wv, bv,
                       eg, ebb, We, be, GW, Av, Cv, q, k, v);
    hipLaunchKernelGGL(k_eattn, dim3(1024), dim3(256), 0, stream,
                       (const float4*)ef, am, GW, Av, Cv, q, (const float4*)k, v, ao);
    hipLaunchKernelGGL(k_projff, dim3(512), dim3(256), 0, stream,
                       ao, Wo, bo, x, fg, fb, W1, b1, W2, b2, (float*)d_out);
}